// Round 8
// baseline (166.739 us; speedup 1.0000x reference)
//
#include <hip/hip_runtime.h>

#define MU_C     0.5f
#define C_NORM_C 8.0f
#define LRELU_C  0.2f
#define NCHEB    6          // degree-6 polynomial; worst-case err ~0.011 << 0.098

constexpr int BB = 16;   // batch
constexpr int KK = 16;   // neighbors
constexpr int EE = 6;    // embedding dim

typedef float v4f __attribute__((ext_vector_type(4)));

// Forced-MLP 16B gather: output reg stays live until the explicit waitcnt,
// so the allocator must keep all batched loads in flight (VGPR count is the
// tell: ~100 = batched; ~32 = compiler serialized them).
__device__ __forceinline__ v4f gload4(const float* p) {
    v4f r;
    asm volatile("global_load_dwordx4 %0, %1, off" : "=v"(r) : "v"(p));
    return r;
}
__device__ __forceinline__ void vmwait() {
    asm volatile("s_waitcnt vmcnt(0)" ::: "memory");
    __builtin_amdgcn_sched_barrier(0);   // rule #18: block VALU hoisting
}

// ws scalar slots: sc[0] = norm accumulator (sum deg^2 + sum w^2)
//                  sc[2] = max_n deg_n (float bits via int atomicMax)

// Chebyshev interval: Gershgorin lambda <= 1 + mu*2*maxdeg_scaled, capped by
// unconditional lambda <= 1 + mu*||L||_F = 1 + mu*8; lambda_min >= 1.
__device__ __forceinline__ void cheb_params(const float* __restrict__ sc,
                                            float& musc, float& theta, float& delta) {
    float scale = C_NORM_C * rsqrtf(sc[0] + 1e-30f);
    musc = MU_C * scale;
    float mdeg = __int_as_float(((const int*)sc)[2]) * scale;
    float lub = 1.f + MU_C * fminf(2.f * mdeg, 8.f);
    theta = 0.5f * (lub + 1.f);
    delta = fmaxf(0.5f * (lub - 1.f), 1e-12f);
}

// f = LeakyReLU(W [x, emb] + b), stored f32 padded (N,16,4) = 256B/node row.
// Block 0 zeroes the scalar slots.
__global__ void k_feat(const float* __restrict__ x,
                       const float* __restrict__ emb,
                       const float* __restrict__ fcw,
                       const float* __restrict__ fcb,
                       float* __restrict__ ffp,
                       float* __restrict__ sc,
                       int N) {
    if (blockIdx.x == 0 && threadIdx.x < 64) sc[threadIdx.x] = 0.f;
    int n = blockIdx.x * blockDim.x + threadIdx.x;
    if (n >= N) return;
    float ev[EE];
#pragma unroll
    for (int j = 0; j < EE; ++j) ev[j] = emb[(size_t)n * EE + j];
    float g[3], w0[3];
#pragma unroll
    for (int f = 0; f < 3; ++f) {
        w0[f] = fcw[f * (EE + 1)];
        float s = fcb[f];
#pragma unroll
        for (int j = 0; j < EE; ++j) s += fcw[f * (EE + 1) + 1 + j] * ev[j];
        g[f] = s;
    }
    float o[BB * 4];
#pragma unroll
    for (int b = 0; b < BB; ++b) {
        float xv = x[(size_t)b * N + n];
#pragma unroll
        for (int f = 0; f < 3; ++f) {
            float v = g[f] + w0[f] * xv;
            o[b * 4 + f] = (v >= 0.f) ? v : LRELU_C * v;
        }
        o[b * 4 + 3] = 0.f;
    }
    float4* dst = (float4*)(ffp + (size_t)n * 64);
#pragma unroll
    for (int q = 0; q < 16; ++q) dst[q] = ((const float4*)o)[q];
}

// Batch-parallel similarity weights. Thread = (node n, batch b).
// 16 asm-batched 16B gathers (16-deep MLP), then 31-shuffle butterfly
// multireduce delivering sum_b exp[] for k=b to lane b.
__global__ void __launch_bounds__(256, 3)
k_weights(const int* __restrict__ nl,
          const float* __restrict__ ffp,
          const float* __restrict__ theta_p,
          float* __restrict__ wl,
          float* __restrict__ sc,
          int N) {
    __shared__ float ldsS[4];
    __shared__ float ldsM[4];
    int t = blockIdx.x * blockDim.x + threadIdx.x;
    int n = t >> 4, b = t & 15;
    bool act = n < N;
    int nc = act ? n : N - 1;
    float inv2t = 0.5f / theta_p[0];
    int kidx = nl[(size_t)nc * KK + b];
    v4f su = *(const v4f*)(ffp + ((size_t)nc << 6) + (b << 2));
    int nbr[16];
#pragma unroll
    for (int k = 0; k < 16; ++k) nbr[k] = __shfl(kidx, k, 16);
    v4f u[16];
#pragma unroll
    for (int k = 0; k < 16; ++k) {
        int nb = nbr[k] < 0 ? 0 : nbr[k];
        u[k] = gload4(ffp + ((size_t)nb << 6) + (b << 2));
    }
    vmwait();
    float v[16];
#pragma unroll
    for (int k = 0; k < 16; ++k) {
        v4f d = su - u[k];
        v[k] = __expf(-(d.x * d.x + d.y * d.y + d.z * d.z) * inv2t);
    }
    // butterfly multireduce: before stage j, v[i] holds partials for
    // k = i*2^j + (b mod 2^j); after stage 3, v[0] = full sum for k=b.
#pragma unroll
    for (int j = 0; j < 4; ++j) {
        int m = 1 << j;
        bool hibit = (b & m) != 0;
#pragma unroll
        for (int i = 0; i < (16 >> (j + 1)); ++i) {
            float lo = v[2 * i], hi = v[2 * i + 1];
            float send = hibit ? lo : hi;
            float rcv = __shfl_xor(send, m, 16);
            v[i] = hibit ? (hi + rcv) : (lo + rcv);
        }
    }
    float myw = v[0] * (1.f / BB);
    if (kidx < 0 || !act) myw = 0.f;
    if (act) wl[(size_t)n * KK + b] = myw;
    float deg = myw, sw2 = myw * myw;
#pragma unroll
    for (int off = 1; off < 16; off <<= 1) {
        deg += __shfl_xor(deg, off, 16);
        sw2 += __shfl_xor(sw2, off, 16);
    }
    float tp = (b == 0) ? (deg * deg + sw2) : 0.f;
    float dm = deg;
    tp += __shfl_xor(tp, 16, 64);
    tp += __shfl_xor(tp, 32, 64);
    dm = fmaxf(dm, __shfl_xor(dm, 16, 64));
    dm = fmaxf(dm, __shfl_xor(dm, 32, 64));
    int lane = threadIdx.x & 63, wid = threadIdx.x >> 6;
    if (lane == 0) { ldsS[wid] = tp; ldsM[wid] = dm; }
    __syncthreads();
    if (threadIdx.x == 0) {
        float ssum = 0.f, smax = 0.f;
#pragma unroll
        for (int wv = 0; wv < 4; ++wv) {
            ssum += ldsS[wv];
            smax = fmaxf(smax, ldsM[wv]);
        }
        atomicAdd(sc, ssum);
        atomicMax((int*)sc + 2, __float_as_int(smax));
    }
}

// Bt = b transposed to (N,16); x1 = b/theta.
__global__ void k_init(const float* __restrict__ x,
                       float* __restrict__ Bt,
                       float* __restrict__ Xb,
                       const float* __restrict__ sc,
                       int N) {
    int t = blockIdx.x * blockDim.x + threadIdx.x;
    if (t >= N * 4) return;
    int n = t >> 2, q = t & 3;
    float musc, theta, delta;
    cheb_params(sc, musc, theta, delta);
    float invt = 1.f / theta;
    v4f bq;
    bq.x = x[(size_t)(q * 4 + 0) * N + n];
    bq.y = x[(size_t)(q * 4 + 1) * N + n];
    bq.z = x[(size_t)(q * 4 + 2) * N + n];
    bq.w = x[(size_t)(q * 4 + 3) * N + n];
    size_t o = (size_t)n * 16 + q * 4;
    *(v4f*)(Bt + o) = bq;
    *(v4f*)(Xb + o) = bq * invt;
}

// Two-term Chebyshev step k (k=1..NCHEB), algebraically identical to the
// (r,p,x) form via p_{k-1} = x_k - x_{k-1}, r_k = b - A x_k:
//   x_{k+1} = x_k + c1*(x_k - x_{k-1}) + c2*(b - A x_k)
//   c1 = rho_k*rho_{k-1}, c2 = 2*rho_k/delta, rho_j = 1/(2*sigma1 - rho_{j-1})
// k==1: x_0 = 0 (skip Xprev read). k==NCHEB: write out transposed.
__global__ void __launch_bounds__(256, 3)
k_cheb(const int* __restrict__ nl,
       const float* __restrict__ wl,
       const float* __restrict__ Xcur,
       float* __restrict__ Xoth,          // holds x_{k-1}; receives x_{k+1}
       const float* __restrict__ Bt,
       const float* __restrict__ sc,
       float* __restrict__ out,
       int N, int k) {
    int t = blockIdx.x * blockDim.x + threadIdx.x;
    if (t >= N * 4) return;
    int n = t >> 2, q = t & 3;
    float musc, theta, delta;
    cheb_params(sc, musc, theta, delta);
    float sig1 = theta / delta;
    float rp = delta / theta;              // rho_0
    float rk = rp;
    for (int j = 1; j <= k; ++j) {
        rk = 1.f / (2.f * sig1 - rp);
        if (j < k) rp = rk;
    }
    float c1 = rk * rp;
    float c2 = 2.f * rk / delta;

    size_t o = (size_t)n * 16 + q * 4;
    v4f xk = *(const v4f*)(Xcur + o);
    int idx[KK];
    float wr[KK];
#pragma unroll
    for (int qq = 0; qq < 4; ++qq) {
        int4 iv = ((const int4*)(nl + (size_t)n * KK))[qq];
        iv.x = iv.x < 0 ? 0 : iv.x;
        iv.y = iv.y < 0 ? 0 : iv.y;
        iv.z = iv.z < 0 ? 0 : iv.z;
        iv.w = iv.w < 0 ? 0 : iv.w;
        ((int4*)idx)[qq] = iv;
        ((float4*)wr)[qq] = ((const float4*)(wl + (size_t)n * KK))[qq];
    }
    v4f v[KK];
#pragma unroll
    for (int kk = 0; kk < KK; ++kk)
        v[kk] = gload4(Xcur + (size_t)idx[kk] * 16 + q * 4);
    v4f bt = *(const v4f*)(Bt + o);
    v4f xp = {0.f, 0.f, 0.f, 0.f};
    if (k > 1) xp = *(const v4f*)(Xoth + o);
    vmwait();

    v4f acc = {0.f, 0.f, 0.f, 0.f};
#pragma unroll
    for (int kk = 0; kk < KK; ++kk)
        acc += (xk - v[kk]) * wr[kk];
    v4f ax = xk + acc * musc;              // A x_k
    v4f xn = xk + (xk - xp) * c1 + (bt - ax) * c2;

    if (k == NCHEB) {
        out[(size_t)(q * 4 + 0) * N + n] = xn.x;
        out[(size_t)(q * 4 + 1) * N + n] = xn.y;
        out[(size_t)(q * 4 + 2) * N + n] = xn.z;
        out[(size_t)(q * 4 + 3) * N + n] = xn.w;
    } else {
        *(v4f*)(Xoth + o) = xn;
    }
}

extern "C" void kernel_launch(void* const* d_in, const int* in_sizes, int n_in,
                              void* d_out, int out_size, void* d_ws, size_t ws_size,
                              hipStream_t stream) {
    const float* x   = (const float*)d_in[0];
    const int*   nl  = (const int*)d_in[1];
    const float* emb = (const float*)d_in[2];
    const float* fcw = (const float*)d_in[3];
    const float* fcb = (const float*)d_in[4];
    const float* th  = (const float*)d_in[5];
    int N = in_sizes[1] / KK;   // 50000

    // ws layout (floats): sc[512] | wl[N*16] | region[N*64]
    //   ffp (f32, N*64) = region, dead after k_weights
    //   Bt = region, Xa = region+16N, Xb = region+32N (written after ffp dead)
    float* sc     = (float*)d_ws;
    float* wl     = sc + 512;
    float* region = wl + (size_t)N * 16;
    float* ffp = region;
    float* Bt  = region;
    float* Xa  = region + (size_t)N * 16;
    float* Xb  = region + (size_t)N * 32;
    float* outp = (float*)d_out;

    int G1 = (N + 255) / 256;
    int GW = (N * 16 + 255) / 256;
    int G4 = (N * 4 + 255) / 256;

    k_feat<<<G1, 256, 0, stream>>>(x, emb, fcw, fcb, ffp, sc, N);
    k_weights<<<GW, 256, 0, stream>>>(nl, ffp, th, wl, sc, N);
    k_init<<<G4, 256, 0, stream>>>(x, Bt, Xb, sc, N);
    for (int k = 1; k <= NCHEB; ++k) {
        const float* Xcur = (k & 1) ? Xb : Xa;   // x_k
        float* Xoth       = (k & 1) ? Xa : Xb;   // x_{k-1} -> x_{k+1}
        k_cheb<<<G4, 256, 0, stream>>>(nl, wl, Xcur, Xoth, Bt, sc, outp, N, k);
    }
}

// Round 9
// 148.015 us; speedup vs baseline: 1.1265x; 1.1265x over previous
//
#include <hip/hip_runtime.h>

#define MU_C     0.5f
#define C_NORM_C 8.0f
#define LRELU_C  0.2f
#define NCHEB    4   // degree-4; worst-case (kappa=5) err 0.043 < 0.098, realistic ~1e-8

constexpr int BB = 16;   // batch
constexpr int KK = 16;   // neighbors
constexpr int EE = 6;    // embedding dim

typedef float v4f __attribute__((ext_vector_type(4)));

// ws scalar slots: sc[0] = norm accumulator (sum deg^2 + sum w^2)
//                  sc[2] = max_n deg_n (float bits via int atomicMax)

// Chebyshev interval: Gershgorin lambda <= 1 + mu*2*maxdeg_scaled, capped by
// unconditional lambda <= 1 + mu*||L||_F = 1 + mu*8; lambda_min >= 1.
__device__ __forceinline__ void cheb_params(const float* __restrict__ sc,
                                            float& musc, float& theta, float& delta) {
    float scale = C_NORM_C * rsqrtf(sc[0] + 1e-30f);
    musc = MU_C * scale;
    float mdeg = __int_as_float(((const int*)sc)[2]) * scale;
    float lub = 1.f + MU_C * fminf(2.f * mdeg, 8.f);
    theta = 0.5f * (lub + 1.f);
    delta = fmaxf(0.5f * (lub - 1.f), 1e-12f);
}

// f = LeakyReLU(W [x, emb] + b), stored f32 padded (N,16,4) = 256B/node row.
// Block 0 zeroes the scalar slots.
__global__ void k_feat(const float* __restrict__ x,
                       const float* __restrict__ emb,
                       const float* __restrict__ fcw,
                       const float* __restrict__ fcb,
                       float* __restrict__ ffp,
                       float* __restrict__ sc,
                       int N) {
    if (blockIdx.x == 0 && threadIdx.x < 64) sc[threadIdx.x] = 0.f;
    int n = blockIdx.x * blockDim.x + threadIdx.x;
    if (n >= N) return;
    float ev[EE];
#pragma unroll
    for (int j = 0; j < EE; ++j) ev[j] = emb[(size_t)n * EE + j];
    float g[3], w0[3];
#pragma unroll
    for (int f = 0; f < 3; ++f) {
        w0[f] = fcw[f * (EE + 1)];
        float s = fcb[f];
#pragma unroll
        for (int j = 0; j < EE; ++j) s += fcw[f * (EE + 1) + 1 + j] * ev[j];
        g[f] = s;
    }
    float o[BB * 4];
#pragma unroll
    for (int b = 0; b < BB; ++b) {
        float xv = x[(size_t)b * N + n];
#pragma unroll
        for (int f = 0; f < 3; ++f) {
            float v = g[f] + w0[f] * xv;
            o[b * 4 + f] = (v >= 0.f) ? v : LRELU_C * v;
        }
        o[b * 4 + 3] = 0.f;
    }
    float4* dst = (float4*)(ffp + (size_t)n * 64);
#pragma unroll
    for (int q = 0; q < 16; ++q) dst[q] = ((const float4*)o)[q];
}

// Batch-parallel similarity weights — round-2 proven form (VGPR ~28, max
// occupancy; TLP beats forced MLP on this latency-bound gather, measured).
// Thread = (node n, batch b); 16-lane group cooperatively gathers each
// neighbor's 256B feature row.
__global__ void k_weights(const int* __restrict__ nl,
                          const float* __restrict__ ffp,
                          const float* __restrict__ theta_p,
                          float* __restrict__ wl,
                          float* __restrict__ sc,
                          int N) {
    __shared__ float ldsS[4];
    __shared__ float ldsM[4];
    int t = blockIdx.x * blockDim.x + threadIdx.x;
    int n = t >> 4, b = t & 15;
    float tp = 0.f, dm = 0.f;
    if (n < N) {
        float inv2t = 0.5f / theta_p[0];
        float4 fs = *(const float4*)(ffp + (size_t)n * 64 + b * 4);
        int kidx = nl[(size_t)n * KK + b];      // lane b holds neighbor index k=b
        int ksafe = kidx < 0 ? 0 : kidx;
        float myw = 0.f;
#pragma unroll
        for (int k = 0; k < KK; ++k) {
            int nbr = __shfl(ksafe, k, 16);     // broadcast k-th neighbor
            float4 fn = *(const float4*)(ffp + (size_t)nbr * 64 + b * 4);
            float d0 = fs.x - fn.x, d1 = fs.y - fn.y, d2 = fs.z - fn.z;
            float e = __expf(-(d0 * d0 + d1 * d1 + d2 * d2) * inv2t);
            e += __shfl_xor(e, 1, 16);
            e += __shfl_xor(e, 2, 16);
            e += __shfl_xor(e, 4, 16);
            e += __shfl_xor(e, 8, 16);
            if (k == b) myw = e * (1.f / BB);
        }
        if (kidx < 0) myw = 0.f;
        wl[(size_t)n * KK + b] = myw;
        float deg = myw, sw2 = myw * myw;
#pragma unroll
        for (int off = 1; off < 16; off <<= 1) {
            deg += __shfl_xor(deg, off, 16);
            sw2 += __shfl_xor(sw2, off, 16);
        }
        tp = (b == 0) ? (deg * deg + sw2) : 0.f;
        dm = deg;
    }
    tp += __shfl_xor(tp, 16, 64);
    tp += __shfl_xor(tp, 32, 64);
    dm = fmaxf(dm, __shfl_xor(dm, 16, 64));
    dm = fmaxf(dm, __shfl_xor(dm, 32, 64));
    int lane = threadIdx.x & 63, wid = threadIdx.x >> 6;
    if (lane == 0) { ldsS[wid] = tp; ldsM[wid] = dm; }
    __syncthreads();
    if (threadIdx.x == 0) {
        float ssum = 0.f, smax = 0.f;
#pragma unroll
        for (int wv = 0; wv < 4; ++wv) {
            ssum += ldsS[wv];
            smax = fmaxf(smax, ldsM[wv]);
        }
        atomicAdd(sc, ssum);
        atomicMax((int*)sc + 2, __float_as_int(smax));
    }
}

// Bt = b transposed to (N,16); x1 = b/theta.
__global__ void k_init(const float* __restrict__ x,
                       float* __restrict__ Bt,
                       float* __restrict__ Xb,
                       const float* __restrict__ sc,
                       int N) {
    int t = blockIdx.x * blockDim.x + threadIdx.x;
    if (t >= N * 4) return;
    int n = t >> 2, q = t & 3;
    float musc, theta, delta;
    cheb_params(sc, musc, theta, delta);
    float invt = 1.f / theta;
    v4f bq;
    bq.x = x[(size_t)(q * 4 + 0) * N + n];
    bq.y = x[(size_t)(q * 4 + 1) * N + n];
    bq.z = x[(size_t)(q * 4 + 2) * N + n];
    bq.w = x[(size_t)(q * 4 + 3) * N + n];
    size_t o = (size_t)n * 16 + q * 4;
    *(v4f*)(Bt + o) = bq;
    *(v4f*)(Xb + o) = bq * invt;
}

// Two-term Chebyshev step k (Saad Alg 12.1 via p_{k-1} = x_k - x_{k-1}):
//   x_{k+1} = x_k + c1*(x_k - x_{k-1}) + c2*(b - A x_k)
//   c1 = rho_k*rho_{k-1}, c2 = 2*rho_k/delta, rho_j = 1/(2*sigma1 - rho_{j-1})
// k==1: x_0 = 0 (skip Xoth read). k==NCHEB: write out transposed, no store.
__global__ void __launch_bounds__(256, 3)
k_cheb(const int* __restrict__ nl,
       const float* __restrict__ wl,
       const float* __restrict__ Xcur,
       float* __restrict__ Xoth,          // holds x_{k-1}; receives x_{k+1}
       const float* __restrict__ Bt,
       const float* __restrict__ sc,
       float* __restrict__ out,
       int N, int k) {
    int t = blockIdx.x * blockDim.x + threadIdx.x;
    if (t >= N * 4) return;
    int n = t >> 2, q = t & 3;
    float musc, theta, delta;
    cheb_params(sc, musc, theta, delta);
    float sig1 = theta / delta;
    float rp = delta / theta;              // rho_0
    float rk = rp;
    for (int j = 1; j <= k; ++j) {
        rk = 1.f / (2.f * sig1 - rp);
        if (j < k) rp = rk;
    }
    float c1 = rk * rp;
    float c2 = 2.f * rk / delta;

    size_t o = (size_t)n * 16 + q * 4;
    v4f xk = *(const v4f*)(Xcur + o);
    int idx[KK];
    float wr[KK];
#pragma unroll
    for (int qq = 0; qq < 4; ++qq) {
        int4 iv = ((const int4*)(nl + (size_t)n * KK))[qq];
        iv.x = iv.x < 0 ? 0 : iv.x;
        iv.y = iv.y < 0 ? 0 : iv.y;
        iv.z = iv.z < 0 ? 0 : iv.z;
        iv.w = iv.w < 0 ? 0 : iv.w;
        ((int4*)idx)[qq] = iv;
        ((float4*)wr)[qq] = ((const float4*)(wl + (size_t)n * KK))[qq];
    }
    v4f v[KK];
#pragma unroll
    for (int kk = 0; kk < KK; ++kk)
        v[kk] = *(const v4f*)(Xcur + (size_t)idx[kk] * 16 + q * 4);
    v4f acc = {0.f, 0.f, 0.f, 0.f};
#pragma unroll
    for (int kk = 0; kk < KK; ++kk)
        acc += (xk - v[kk]) * wr[kk];
    v4f ax = xk + acc * musc;              // A x_k
    v4f bt = *(const v4f*)(Bt + o);
    v4f xp = {0.f, 0.f, 0.f, 0.f};
    if (k > 1) xp = *(const v4f*)(Xoth + o);
    v4f xn = xk + (xk - xp) * c1 + (bt - ax) * c2;

    if (k == NCHEB) {
        out[(size_t)(q * 4 + 0) * N + n] = xn.x;
        out[(size_t)(q * 4 + 1) * N + n] = xn.y;
        out[(size_t)(q * 4 + 2) * N + n] = xn.z;
        out[(size_t)(q * 4 + 3) * N + n] = xn.w;
    } else {
        *(v4f*)(Xoth + o) = xn;
    }
}

extern "C" void kernel_launch(void* const* d_in, const int* in_sizes, int n_in,
                              void* d_out, int out_size, void* d_ws, size_t ws_size,
                              hipStream_t stream) {
    const float* x   = (const float*)d_in[0];
    const int*   nl  = (const int*)d_in[1];
    const float* emb = (const float*)d_in[2];
    const float* fcw = (const float*)d_in[3];
    const float* fcb = (const float*)d_in[4];
    const float* th  = (const float*)d_in[5];
    int N = in_sizes[1] / KK;   // 50000

    // ws layout (floats): sc[512] | wl[N*16] | region[N*64]
    //   ffp (f32, N*64) = region, dead after k_weights
    //   Bt = region, Xa = region+16N, Xb = region+32N (written after ffp dead)
    float* sc     = (float*)d_ws;
    float* wl     = sc + 512;
    float* region = wl + (size_t)N * 16;
    float* ffp = region;
    float* Bt  = region;
    float* Xa  = region + (size_t)N * 16;
    float* Xb  = region + (size_t)N * 32;
    float* outp = (float*)d_out;

    int G1 = (N + 255) / 256;
    int GW = (N * 16 + 255) / 256;
    int G4 = (N * 4 + 255) / 256;

    k_feat<<<G1, 256, 0, stream>>>(x, emb, fcw, fcb, ffp, sc, N);
    k_weights<<<GW, 256, 0, stream>>>(nl, ffp, th, wl, sc, N);
    k_init<<<G4, 256, 0, stream>>>(x, Bt, Xb, sc, N);
    for (int k = 1; k <= NCHEB; ++k) {
        const float* Xcur = (k & 1) ? Xb : Xa;   // x_k
        float* Xoth       = (k & 1) ? Xa : Xb;   // x_{k-1} -> x_{k+1}
        k_cheb<<<G4, 256, 0, stream>>>(nl, wl, Xcur, Xoth, Bt, sc, outp, N, k);
    }
}